// Round 4
// baseline (42.637 us; speedup 1.0000x reference)
//
#include <hip/hip_runtime.h>
#include <hip/hip_bf16.h>

typedef int   v4i __attribute__((ext_vector_type(4)));
typedef float v4f __attribute__((ext_vector_type(4)));

#define HWSZ 3136   // 56*56
#define IMW  56
#define PADW 58     // 56+2 halo
#define PHW  3364   // 58*58
#define CIN  64
#define COUT 128

__device__ __forceinline__ float step_size(float a) {
    a = a > 0.f ? a : 0.f;              // relu(alpha)
    return 2.0f * a / 254.0f;
}

__device__ __forceinline__ int quant1(float x, float s) {
    float v = rintf(x / s);             // round-half-even like jnp.round
    v = fminf(127.f, fmaxf(-127.f, v)); // clip(-127, 127)
    return (int)v;
}

// ---------------- fused quantize ----------------
// blocks 0..1567   : x NCHW fp32 -> padded NHWC int8 (32 n * 49 hw-tiles)
// blocks 1568..1855: w OIHW -> wt[o][tap][c]
// blocks 1856..1969: zero the 1-px halo of cx
__global__ __launch_bounds__(256) void quant_kernel(const float* __restrict__ x,
                                                    const float* __restrict__ w,
                                                    const float* __restrict__ alpha_x,
                                                    const float* __restrict__ alpha_w,
                                                    signed char* __restrict__ cx,
                                                    signed char* __restrict__ wt) {
    int t = threadIdx.x;
    if (blockIdx.x >= 1856) {
        // pad zeroing: 32 n * 228 pad px * 4 segs = 29184 16B-slots
        int q = (blockIdx.x - 1856) * 256 + t;
        int n = q / 912;
        int r = q % 912;
        int px = r >> 2, seg = r & 3;
        int ph, pw;
        if (px < 58)       { ph = 0;  pw = px; }
        else if (px < 116) { ph = 57; pw = px - 58; }
        else { int k = px - 116; ph = 1 + (k >> 1); pw = (k & 1) * 57; }
        v4i z = {0, 0, 0, 0};
        *(v4i*)(cx + ((size_t)n * PHW + ph * PADW + pw) * 64 + seg * 16) = z;
        return;
    }
    if (blockIdx.x >= 1568) {
        float s = step_size(alpha_w[0]);
        int j = (blockIdx.x - 1568) * 256 + t;   // wt flat index, 73728 total
        int o = j / 576;
        int r = j % 576;
        int tap = r >> 6;
        int c   = r & 63;
        float v = w[((size_t)o * 64 + c) * 9 + tap];
        wt[j] = (signed char)quant1(v, s);
        return;
    }
    __shared__ signed char tile[64 * 68];
    float s = step_size(alpha_x[0]);
    int n   = blockIdx.x / 49;
    int hw0 = (blockIdx.x % 49) * 64;
    int hwl = t & 63;
    int cb  = t >> 6;

    const float* xb = x + (size_t)n * (CIN * HWSZ) + hw0 + hwl;
#pragma unroll
    for (int i = 0; i < 16; ++i) {
        int c = cb * 16 + i;
        float v = xb[(size_t)c * HWSZ];
        tile[hwl * 68 + c] = (signed char)quant1(v, s);
    }
    __syncthreads();

    int p = t >> 2, seg = t & 3;                 // pixel within tile, 16B segment
    const unsigned int* lp = (const unsigned int*)tile;
    int base = (p * 68 + seg * 16) >> 2;
    v4i val;
    val[0] = (int)lp[base + 0];
    val[1] = (int)lp[base + 1];
    val[2] = (int)lp[base + 2];
    val[3] = (int)lp[base + 3];
    int hw = hw0 + p;
    int h = hw / IMW, wq = hw % IMW;
    *(v4i*)(cx + ((size_t)n * PHW + (h + 1) * PADW + (wq + 1)) * 64 + seg * 16) = val;
}

// ---------------- int8 implicit-GEMM conv, padded input ----------------
// block = 256 (4 waves) -> 128 px x 128 o; wave = 64 px x 64 o
// grid = 100352/128 = 784
__global__ __launch_bounds__(256) void conv_kernel(const signed char* __restrict__ cx,
                                                   const signed char* __restrict__ wt,
                                                   const float* __restrict__ ax,
                                                   const float* __restrict__ aw,
                                                   float* __restrict__ out) {
    float scale = step_size(ax[0]) * step_size(aw[0]);
    int tid  = threadIdx.x;
    int lane = tid & 63;
    int wid  = tid >> 6;
    int row  = lane & 15;   // A: pixel within 16-tile; B: o within 16-tile
    int kg   = lane >> 4;   // 16-byte k-chunk within the tap's 64 channels
    int wp   = wid >> 1;
    int wo   = wid & 1;
    int pbase = blockIdx.x * 128 + wp * 64;
    int obase = wo * 64;

    // per-pixel-tile padded base pointers (center tap)
    const signed char* xb[4];
#pragma unroll
    for (int pt = 0; pt < 4; ++pt) {
        int p  = pbase + pt * 16 + row;
        int n  = p / HWSZ;
        int hw = p % HWSZ;
        int h  = hw / IMW, wq = hw % IMW;
        xb[pt] = cx + ((size_t)n * PHW + (h + 1) * PADW + (wq + 1)) * 64 + kg * 16;
    }
    const signed char* wb = wt + ((size_t)(obase + row) * 9) * 64 + kg * 16;

    v4i acc[4][4] = {};

#pragma unroll
    for (int tap = 0; tap < 9; ++tap) {
        int doff = ((tap / 3 - 1) * PADW + (tap % 3 - 1)) * 64;  // compile-time const
        v4i a[4];
#pragma unroll
        for (int pt = 0; pt < 4; ++pt)
            a[pt] = *(const v4i*)(xb[pt] + doff);
        v4i b[4];
#pragma unroll
        for (int ot = 0; ot < 4; ++ot)
            b[ot] = *(const v4i*)(wb + (ot * 16 * 9) * 64 + tap * 64);
#pragma unroll
        for (int pt = 0; pt < 4; ++pt)
#pragma unroll
            for (int ot = 0; ot < 4; ++ot)
                acc[pt][ot] = __builtin_amdgcn_mfma_i32_16x16x64_i8(a[pt], b[ot], acc[pt][ot], 0, 0, 0);
    }

    // epilogue: D row = (lane>>4)*4+reg = pixel, col = lane&15 = o
#pragma unroll
    for (int pt = 0; pt < 4; ++pt) {
        int p4 = pbase + pt * 16 + kg * 4;   // 4 consecutive pixels, same n
        int n  = p4 / HWSZ;
        int hw = p4 % HWSZ;
#pragma unroll
        for (int ot = 0; ot < 4; ++ot) {
            int o = obase + ot * 16 + row;
            v4f v;
            v[0] = scale * (float)acc[pt][ot][0];
            v[1] = scale * (float)acc[pt][ot][1];
            v[2] = scale * (float)acc[pt][ot][2];
            v[3] = scale * (float)acc[pt][ot][3];
            __builtin_nontemporal_store(v, (v4f*)(out + ((size_t)n * COUT + o) * HWSZ + hw));
        }
    }
}

extern "C" void kernel_launch(void* const* d_in, const int* in_sizes, int n_in,
                              void* d_out, int out_size, void* d_ws, size_t ws_size,
                              hipStream_t stream) {
    const float* x  = (const float*)d_in[0];
    const float* w  = (const float*)d_in[1];
    const float* ax = (const float*)d_in[2];
    const float* aw = (const float*)d_in[3];
    float* out = (float*)d_out;

    signed char* cx = (signed char*)d_ws;   // 32*3364*64 = 6,889,472 B (padded NHWC)
    signed char* wt = cx + 6889472;         // 128*9*64   =    73,728 B

    quant_kernel<<<1970, 256, 0, stream>>>(x, w, ax, aw, cx, wt);
    conv_kernel<<<784, 256, 0, stream>>>(cx, wt, ax, aw, out);
}

// Round 5
// 41.671 us; speedup vs baseline: 1.0232x; 1.0232x over previous
//
#include <hip/hip_runtime.h>
#include <hip/hip_bf16.h>

typedef int   v4i __attribute__((ext_vector_type(4)));
typedef float v4f __attribute__((ext_vector_type(4)));

#define HWSZ 3136   // 56*56
#define IMW  56
#define PADW 58     // 56+2 halo
#define PHW  3364   // 58*58
#define CIN  64
#define COUT 128

__device__ __forceinline__ float step_size(float a) {
    a = a > 0.f ? a : 0.f;              // relu(alpha)
    return 2.0f * a / 254.0f;
}

__device__ __forceinline__ int quant1(float x, float s) {
    float v = rintf(x / s);             // round-half-even like jnp.round
    v = fminf(127.f, fmaxf(-127.f, v)); // clip(-127, 127)
    return (int)v;
}

__device__ __forceinline__ unsigned int pack4(int a, int b, int c, int d) {
    return (unsigned int)(a & 255) | ((unsigned int)(b & 255) << 8) |
           ((unsigned int)(c & 255) << 16) | ((unsigned int)(d & 255) << 24);
}

// ---------------- fused quantize ----------------
// blocks 0..391  : x NCHW fp32 -> padded NHWC int8 (8 n-quads * 49 hw-tiles)
// blocks 392..679: w OIHW -> wt[o][tap][c]
// blocks 680..793: zero the 1-px halo of cx
__global__ __launch_bounds__(256) void quant_kernel(const float* __restrict__ x,
                                                    const float* __restrict__ w,
                                                    const float* __restrict__ alpha_x,
                                                    const float* __restrict__ alpha_w,
                                                    signed char* __restrict__ cx,
                                                    signed char* __restrict__ wt) {
    int t = threadIdx.x;
    int b = blockIdx.x;
    if (b >= 392) {
        if (b >= 680) {
            // pad zeroing: 32 n * 228 pad px * 4 segs = 29184 16B-slots
            int q = (b - 680) * 256 + t;
            int n = q / 912;
            int r = q % 912;
            int px = r >> 2, seg = r & 3;
            int ph, pw;
            if (px < 58)       { ph = 0;  pw = px; }
            else if (px < 116) { ph = 57; pw = px - 58; }
            else { int k = px - 116; ph = 1 + (k >> 1); pw = (k & 1) * 57; }
            v4i z = {0, 0, 0, 0};
            *(v4i*)(cx + ((size_t)n * PHW + ph * PADW + pw) * 64 + seg * 16) = z;
            return;
        }
        float s = step_size(alpha_w[0]);
        int j = (b - 392) * 256 + t;   // wt flat index, 73728 total
        int o = j / 576;
        int r = j % 576;
        int tap = r >> 6;
        int c   = r & 63;
        float v = w[((size_t)o * 64 + c) * 9 + tap];
        wt[j] = (signed char)quant1(v, s);
        return;
    }

    // x path: block covers 4 n-slices of a 64-px tile, 64 channels
    __shared__ unsigned int tile32[64 * 17];   // 64 px x 68 B (17 dwords)
    float s = step_size(alpha_x[0]);
    int nb  = b / 49;
    int hw0 = (b % 49) * 64;
    int g   = t & 15;       // px group (4 px)
    int cq  = t >> 4;       // channel quad (4 c)
    int p   = t >> 2;       // readback: pixel
    int seg = t & 3;        // readback: 16B segment
    int hw  = hw0 + p;
    int h   = hw / IMW, wq = hw % IMW;
    signed char* cxp = cx + ((size_t)(h + 1) * PADW + (wq + 1)) * 64 + seg * 16;

#pragma unroll
    for (int i = 0; i < 4; ++i) {
        int n = nb * 4 + i;
        const float* xb = x + ((size_t)n * CIN + cq * 4) * HWSZ + hw0 + g * 4;
        v4f f0 = *(const v4f*)(xb);
        v4f f1 = *(const v4f*)(xb + HWSZ);
        v4f f2 = *(const v4f*)(xb + 2 * HWSZ);
        v4f f3 = *(const v4f*)(xb + 3 * HWSZ);
        if (i) __syncthreads();   // previous iteration's readback done
#pragma unroll
        for (int j = 0; j < 4; ++j) {
            unsigned int u = pack4(quant1(f0[j], s), quant1(f1[j], s),
                                   quant1(f2[j], s), quant1(f3[j], s));
            tile32[(g * 4 + j) * 17 + cq] = u;
        }
        __syncthreads();
        int base = p * 17 + seg * 4;
        v4i val;
        val[0] = (int)tile32[base + 0];
        val[1] = (int)tile32[base + 1];
        val[2] = (int)tile32[base + 2];
        val[3] = (int)tile32[base + 3];
        *(v4i*)(cxp + (size_t)n * PHW * 64) = val;
    }
}

// ---------------- int8 implicit-GEMM conv, padded input (UNCHANGED from R4) ----------------
__global__ __launch_bounds__(256) void conv_kernel(const signed char* __restrict__ cx,
                                                   const signed char* __restrict__ wt,
                                                   const float* __restrict__ ax,
                                                   const float* __restrict__ aw,
                                                   float* __restrict__ out) {
    float scale = step_size(ax[0]) * step_size(aw[0]);
    int tid  = threadIdx.x;
    int lane = tid & 63;
    int wid  = tid >> 6;
    int row  = lane & 15;
    int kg   = lane >> 4;
    int wp   = wid >> 1;
    int wo   = wid & 1;
    int pbase = blockIdx.x * 128 + wp * 64;
    int obase = wo * 64;

    const signed char* xb[4];
#pragma unroll
    for (int pt = 0; pt < 4; ++pt) {
        int p  = pbase + pt * 16 + row;
        int n  = p / HWSZ;
        int hw = p % HWSZ;
        int h  = hw / IMW, wq = hw % IMW;
        xb[pt] = cx + ((size_t)n * PHW + (h + 1) * PADW + (wq + 1)) * 64 + kg * 16;
    }
    const signed char* wb = wt + ((size_t)(obase + row) * 9) * 64 + kg * 16;

    v4i acc[4][4] = {};

#pragma unroll
    for (int tap = 0; tap < 9; ++tap) {
        int doff = ((tap / 3 - 1) * PADW + (tap % 3 - 1)) * 64;
        v4i a[4];
#pragma unroll
        for (int pt = 0; pt < 4; ++pt)
            a[pt] = *(const v4i*)(xb[pt] + doff);
        v4i b[4];
#pragma unroll
        for (int ot = 0; ot < 4; ++ot)
            b[ot] = *(const v4i*)(wb + (ot * 16 * 9) * 64 + tap * 64);
#pragma unroll
        for (int pt = 0; pt < 4; ++pt)
#pragma unroll
            for (int ot = 0; ot < 4; ++ot)
                acc[pt][ot] = __builtin_amdgcn_mfma_i32_16x16x64_i8(a[pt], b[ot], acc[pt][ot], 0, 0, 0);
    }

#pragma unroll
    for (int pt = 0; pt < 4; ++pt) {
        int p4 = pbase + pt * 16 + kg * 4;
        int n  = p4 / HWSZ;
        int hw = p4 % HWSZ;
#pragma unroll
        for (int ot = 0; ot < 4; ++ot) {
            int o = obase + ot * 16 + row;
            v4f v;
            v[0] = scale * (float)acc[pt][ot][0];
            v[1] = scale * (float)acc[pt][ot][1];
            v[2] = scale * (float)acc[pt][ot][2];
            v[3] = scale * (float)acc[pt][ot][3];
            __builtin_nontemporal_store(v, (v4f*)(out + ((size_t)n * COUT + o) * HWSZ + hw));
        }
    }
}

extern "C" void kernel_launch(void* const* d_in, const int* in_sizes, int n_in,
                              void* d_out, int out_size, void* d_ws, size_t ws_size,
                              hipStream_t stream) {
    const float* x  = (const float*)d_in[0];
    const float* w  = (const float*)d_in[1];
    const float* ax = (const float*)d_in[2];
    const float* aw = (const float*)d_in[3];
    float* out = (float*)d_out;

    signed char* cx = (signed char*)d_ws;   // 32*3364*64 = 6,889,472 B (padded NHWC)
    signed char* wt = cx + 6889472;         // 128*9*64   =    73,728 B

    quant_kernel<<<794, 256, 0, stream>>>(x, w, ax, aw, cx, wt);
    conv_kernel<<<784, 256, 0, stream>>>(cx, wt, ax, aw, out);
}

// Round 6
// 38.417 us; speedup vs baseline: 1.1098x; 1.0847x over previous
//
#include <hip/hip_runtime.h>
#include <hip/hip_bf16.h>

typedef int   v4i __attribute__((ext_vector_type(4)));
typedef float v4f __attribute__((ext_vector_type(4)));

#define HWSZ 3136   // 56*56
#define IMW  56
#define PADW 58     // 56+2 halo
#define PHW  3364   // 58*58
#define CIN  64
#define COUT 128

__device__ __forceinline__ float step_size(float a) {
    a = a > 0.f ? a : 0.f;              // relu(alpha)
    return 2.0f * a / 254.0f;
}

__device__ __forceinline__ int quant1(float x, float s) {
    float v = rintf(x / s);             // round-half-even like jnp.round
    v = fminf(127.f, fmaxf(-127.f, v)); // clip(-127, 127)
    return (int)v;
}

__device__ __forceinline__ unsigned int pack4(int a, int b, int c, int d) {
    return (unsigned int)(a & 255) | ((unsigned int)(b & 255) << 8) |
           ((unsigned int)(c & 255) << 16) | ((unsigned int)(d & 255) << 24);
}

// ---------------- fused quantize (UNCHANGED from R5) ----------------
__global__ __launch_bounds__(256) void quant_kernel(const float* __restrict__ x,
                                                    const float* __restrict__ w,
                                                    const float* __restrict__ alpha_x,
                                                    const float* __restrict__ alpha_w,
                                                    signed char* __restrict__ cx,
                                                    signed char* __restrict__ wt) {
    int t = threadIdx.x;
    int b = blockIdx.x;
    if (b >= 392) {
        if (b >= 680) {
            int q = (b - 680) * 256 + t;
            int n = q / 912;
            int r = q % 912;
            int px = r >> 2, seg = r & 3;
            int ph, pw;
            if (px < 58)       { ph = 0;  pw = px; }
            else if (px < 116) { ph = 57; pw = px - 58; }
            else { int k = px - 116; ph = 1 + (k >> 1); pw = (k & 1) * 57; }
            v4i z = {0, 0, 0, 0};
            *(v4i*)(cx + ((size_t)n * PHW + ph * PADW + pw) * 64 + seg * 16) = z;
            return;
        }
        float s = step_size(alpha_w[0]);
        int j = (b - 392) * 256 + t;
        int o = j / 576;
        int r = j % 576;
        int tap = r >> 6;
        int c   = r & 63;
        float v = w[((size_t)o * 64 + c) * 9 + tap];
        wt[j] = (signed char)quant1(v, s);
        return;
    }

    __shared__ unsigned int tile32[64 * 17];
    float s = step_size(alpha_x[0]);
    int nb  = b / 49;
    int hw0 = (b % 49) * 64;
    int g   = t & 15;
    int cq  = t >> 4;
    int p   = t >> 2;
    int seg = t & 3;
    int hw  = hw0 + p;
    int h   = hw / IMW, wq = hw % IMW;
    signed char* cxp = cx + ((size_t)(h + 1) * PADW + (wq + 1)) * 64 + seg * 16;

#pragma unroll
    for (int i = 0; i < 4; ++i) {
        int n = nb * 4 + i;
        const float* xb = x + ((size_t)n * CIN + cq * 4) * HWSZ + hw0 + g * 4;
        v4f f0 = *(const v4f*)(xb);
        v4f f1 = *(const v4f*)(xb + HWSZ);
        v4f f2 = *(const v4f*)(xb + 2 * HWSZ);
        v4f f3 = *(const v4f*)(xb + 3 * HWSZ);
        if (i) __syncthreads();
#pragma unroll
        for (int j = 0; j < 4; ++j) {
            unsigned int u = pack4(quant1(f0[j], s), quant1(f1[j], s),
                                   quant1(f2[j], s), quant1(f3[j], s));
            tile32[(g * 4 + j) * 17 + cq] = u;
        }
        __syncthreads();
        int base = p * 17 + seg * 4;
        v4i val;
        val[0] = (int)tile32[base + 0];
        val[1] = (int)tile32[base + 1];
        val[2] = (int)tile32[base + 2];
        val[3] = (int)tile32[base + 3];
        *(v4i*)(cxp + (size_t)n * PHW * 64) = val;
    }
}

// ---------------- int8 implicit-GEMM conv ----------------
// 2 waves/block: block = 64 px x 128 o, wave = 64 px x 64 o
// grid = 100352/64 = 1568 (6.125 blocks/CU, 1568%8==0 for XCD swizzle)
__global__ __launch_bounds__(128) void conv_kernel(const signed char* __restrict__ cx,
                                                   const signed char* __restrict__ wt,
                                                   const float* __restrict__ ax,
                                                   const float* __restrict__ aw,
                                                   float* __restrict__ out) {
    float scale = step_size(ax[0]) * step_size(aw[0]);
    int tid  = threadIdx.x;
    int lane = tid & 63;
    int wid  = tid >> 6;    // 0..1 -> o half
    int row  = lane & 15;
    int kg   = lane >> 4;

    // XCD-aware swizzle: XCD k gets contiguous tiles [k*196, (k+1)*196)
    int bid  = blockIdx.x;
    int swz  = (bid & 7) * 196 + (bid >> 3);
    int pbase = swz * 64;
    int obase = wid * 64;

    const signed char* xb[4];
#pragma unroll
    for (int pt = 0; pt < 4; ++pt) {
        int p  = pbase + pt * 16 + row;
        int n  = p / HWSZ;
        int hw = p % HWSZ;
        int h  = hw / IMW, wq = hw % IMW;
        xb[pt] = cx + ((size_t)n * PHW + (h + 1) * PADW + (wq + 1)) * 64 + kg * 16;
    }
    const signed char* wb = wt + ((size_t)(obase + row) * 9) * 64 + kg * 16;

    v4i acc[4][4] = {};

#pragma unroll
    for (int tap = 0; tap < 9; ++tap) {
        int doff = ((tap / 3 - 1) * PADW + (tap % 3 - 1)) * 64;
        v4i a[4];
#pragma unroll
        for (int pt = 0; pt < 4; ++pt)
            a[pt] = *(const v4i*)(xb[pt] + doff);
        v4i b[4];
#pragma unroll
        for (int ot = 0; ot < 4; ++ot)
            b[ot] = *(const v4i*)(wb + (ot * 16 * 9) * 64 + tap * 64);
#pragma unroll
        for (int pt = 0; pt < 4; ++pt)
#pragma unroll
            for (int ot = 0; ot < 4; ++ot)
                acc[pt][ot] = __builtin_amdgcn_mfma_i32_16x16x64_i8(a[pt], b[ot], acc[pt][ot], 0, 0, 0);
    }

    // epilogue: plain stores -> L2 assembles full 128B lines (block covers 64 px/o)
#pragma unroll
    for (int pt = 0; pt < 4; ++pt) {
        int p4 = pbase + pt * 16 + kg * 4;
        int n  = p4 / HWSZ;
        int hw = p4 % HWSZ;
#pragma unroll
        for (int ot = 0; ot < 4; ++ot) {
            int o = obase + ot * 16 + row;
            v4f v;
            v[0] = scale * (float)acc[pt][ot][0];
            v[1] = scale * (float)acc[pt][ot][1];
            v[2] = scale * (float)acc[pt][ot][2];
            v[3] = scale * (float)acc[pt][ot][3];
            *(v4f*)(out + ((size_t)n * COUT + o) * HWSZ + hw) = v;
        }
    }
}

extern "C" void kernel_launch(void* const* d_in, const int* in_sizes, int n_in,
                              void* d_out, int out_size, void* d_ws, size_t ws_size,
                              hipStream_t stream) {
    const float* x  = (const float*)d_in[0];
    const float* w  = (const float*)d_in[1];
    const float* ax = (const float*)d_in[2];
    const float* aw = (const float*)d_in[3];
    float* out = (float*)d_out;

    signed char* cx = (signed char*)d_ws;   // 32*3364*64 = 6,889,472 B (padded NHWC)
    signed char* wt = cx + 6889472;         // 128*9*64   =    73,728 B

    quant_kernel<<<794, 256, 0, stream>>>(x, w, ax, aw, cx, wt);
    conv_kernel<<<1568, 128, 0, stream>>>(cx, wt, ax, aw, out);
}